// Round 1
// baseline (558.567 us; speedup 1.0000x reference)
//
#include <hip/hip_runtime.h>
#include <hip/hip_bf16.h>

#define KREAL 4369
#define KP    4416   // 69 * 64
#define NDIM  4096
#define MROWS 8192

typedef unsigned short u16;
typedef __attribute__((ext_vector_type(8))) __bf16 bf16x8;
typedef __attribute__((ext_vector_type(8))) u16 u16x8;
typedef __attribute__((ext_vector_type(4))) float f32x4;

__device__ __forceinline__ u16 bf16rne(float f) {
  unsigned int u = __builtin_bit_cast(unsigned int, f);
  u += 0x7fffu + ((u >> 16) & 1u);
  return (u16)(u >> 16);
}

// ---------------- feature kernel: xb[row][t] = bf16(polyfeat(z_row)[t]) ----------------
__global__ void feat_kernel(const float* __restrict__ z, u16* __restrict__ xb) {
  const int row = blockIdx.x;
  const int tid = threadIdx.x;
  float zr[16];
#pragma unroll
  for (int i = 0; i < 16; ++i) zr[i] = z[row * 16 + i];
  u16* xrow = xb + (size_t)row * KP;
  for (int g = tid; g < KP / 8; g += 256) {
    u16x8 pack;
#pragma unroll
    for (int e = 0; e < 8; ++e) {
      int t = g * 8 + e;
      float v;
      if (t >= KREAL) v = 0.0f;
      else if (t == 0) v = 1.0f;
      else if (t < 17) v = zr[t - 1];
      else if (t < 273) { int u = t - 17; v = zr[u >> 4] * zr[u & 15]; }
      else { int u = t - 273; v = zr[(u >> 8) & 15] * (zr[(u >> 4) & 15] * zr[u & 15]); }
      pack[e] = bf16rne(v);
    }
    *reinterpret_cast<u16x8*>(xrow + g * 8) = pack;
  }
}

// ------- W convert+transpose: wbt[d][t] = bf16(W[t][d] + (t==0 ? b[d] : 0)), t>=KREAL -> 0 -------
__global__ void wconv_kernel(const float* __restrict__ W, const float* __restrict__ bias,
                             u16* __restrict__ wbt) {
  __shared__ float tile[64][65];
  const int t0 = blockIdx.x * 64;
  const int d0 = blockIdx.y * 64;
  const int tid = threadIdx.x;
  const int dloc = tid & 63;
  const int rbase = tid >> 6;  // 0..3
#pragma unroll
  for (int rr = 0; rr < 16; ++rr) {
    const int r = rr * 4 + rbase;
    const int t = t0 + r;
    float v = 0.0f;
    if (t < KREAL) {
      v = W[(size_t)t * NDIM + d0 + dloc];
      if (t == 0) v += bias[d0 + dloc];
    }
    tile[r][dloc] = v;
  }
  __syncthreads();
#pragma unroll
  for (int round = 0; round < 2; ++round) {
    const int v = round * 256 + tid;
    const int d = v >> 3;   // 0..63
    const int tg = v & 7;   // 0..7
    u16x8 pack;
#pragma unroll
    for (int e = 0; e < 8; ++e) pack[e] = bf16rne(tile[tg * 8 + e][d]);
    *reinterpret_cast<u16x8*>(wbt + (size_t)(d0 + d) * KP + t0 + tg * 8) = pack;
  }
}

// ---------------- GEMM: out = xb @ wbt^T (bias already folded into wbt row t=0) ----------------
#define GLOAD(gp, lp)                                                                     \
  __builtin_amdgcn_global_load_lds((const __attribute__((address_space(1))) unsigned int*)(gp), \
                                   (__attribute__((address_space(3))) unsigned int*)(lp), 16, 0, 0)

__global__ __launch_bounds__(256) void gemm_kernel(const u16* __restrict__ xb,
                                                   const u16* __restrict__ wbt,
                                                   float* __restrict__ out) {
  __shared__ u16 As[128 * 64];
  __shared__ u16 Bs[128 * 64];

  // bijective XCD swizzle (nwg = 2048, 2048 % 8 == 0)
  const int bid = blockIdx.x;
  const int swz = (bid & 7) * (2048 >> 3) + (bid >> 3);
  const int mt = swz >> 5;   // 64 M-tiles
  const int nt = swz & 31;   // 32 N-tiles
  const int brow = mt * 128;
  const int bcol = nt * 128;

  const int tid  = threadIdx.x;
  const int lane = tid & 63;
  const int wid  = tid >> 6;
  const int wr   = wid >> 1;
  const int wc   = wid & 1;

  // staging: chunk c = wid*4+j covers LDS u16 elems [c*512, c*512+512)
  //   -> tile row = c*8 + (lane>>3), col8 = (lane&7)*8 (lane writes 16 B at base + lane*16)
  const u16* gA = xb  + (size_t)(brow + wid * 32 + (lane >> 3)) * KP + (lane & 7) * 8;
  const u16* gB = wbt + (size_t)(bcol + wid * 32 + (lane >> 3)) * KP + (lane & 7) * 8;
  u16* lA = As + wid * 4 * 512;
  u16* lB = Bs + wid * 4 * 512;

  f32x4 acc[4][4] = {};

  for (int k0 = 0; k0 < KP; k0 += 64) {
    __syncthreads();
#pragma unroll
    for (int j = 0; j < 4; ++j) GLOAD(gA + (size_t)j * 8 * KP + k0, lA + j * 512);
#pragma unroll
    for (int j = 0; j < 4; ++j) GLOAD(gB + (size_t)j * 8 * KP + k0, lB + j * 512);
    asm volatile("s_waitcnt vmcnt(0)" ::: "memory");
    __syncthreads();

#pragma unroll
    for (int kk = 0; kk < 2; ++kk) {
      const int krow = kk * 32 + (lane >> 4) * 8;
      bf16x8 af[4], bfr[4];
#pragma unroll
      for (int mi = 0; mi < 4; ++mi)
        af[mi] = *reinterpret_cast<const bf16x8*>(As + (wr * 64 + mi * 16 + (lane & 15)) * 64 + krow);
#pragma unroll
      for (int ni = 0; ni < 4; ++ni)
        bfr[ni] = *reinterpret_cast<const bf16x8*>(Bs + (wc * 64 + ni * 16 + (lane & 15)) * 64 + krow);
#pragma unroll
      for (int mi = 0; mi < 4; ++mi)
#pragma unroll
        for (int ni = 0; ni < 4; ++ni)
          acc[mi][ni] = __builtin_amdgcn_mfma_f32_16x16x32_bf16(af[mi], bfr[ni], acc[mi][ni], 0, 0, 0);
    }
  }

  // C/D layout (m89-verified): col = lane&15, row = (lane>>4)*4 + j
  const int r0 = brow + wr * 64 + ((lane >> 4) << 2);
  const int c0 = bcol + wc * 64 + (lane & 15);
#pragma unroll
  for (int mi = 0; mi < 4; ++mi)
#pragma unroll
    for (int ni = 0; ni < 4; ++ni) {
#pragma unroll
      for (int j = 0; j < 4; ++j)
        out[(size_t)(r0 + mi * 16 + j) * NDIM + (c0 + ni * 16)] = acc[mi][ni][j];
    }
}

// ---------------- fallback (ws too small): correct fp32 path ----------------
__global__ void fallback_kernel(const float* __restrict__ z, const float* __restrict__ W,
                                const float* __restrict__ bias, float* __restrict__ out) {
  __shared__ float feat[KREAL];
  const int row = blockIdx.x;
  const int tid = threadIdx.x;
  float zr[16];
#pragma unroll
  for (int i = 0; i < 16; ++i) zr[i] = z[row * 16 + i];
  for (int t = tid; t < KREAL; t += 256) {
    float v;
    if (t == 0) v = 1.0f;
    else if (t < 17) v = zr[t - 1];
    else if (t < 273) { int u = t - 17; v = zr[u >> 4] * zr[u & 15]; }
    else { int u = t - 273; v = zr[(u >> 8) & 15] * (zr[(u >> 4) & 15] * zr[u & 15]); }
    feat[t] = v;
  }
  __syncthreads();
  float acc[16];
#pragma unroll
  for (int j = 0; j < 16; ++j) acc[j] = bias[tid + 256 * j];
  for (int t = 0; t < KREAL; ++t) {
    const float f = feat[t];
    const float* wrow = W + (size_t)t * NDIM;
#pragma unroll
    for (int j = 0; j < 16; ++j) acc[j] = fmaf(f, wrow[tid + 256 * j], acc[j]);
  }
  float* orow = out + (size_t)row * NDIM;
#pragma unroll
  for (int j = 0; j < 16; ++j) orow[tid + 256 * j] = acc[j];
}

extern "C" void kernel_launch(void* const* d_in, const int* in_sizes, int n_in,
                              void* d_out, int out_size, void* d_ws, size_t ws_size,
                              hipStream_t stream) {
  const float* z = (const float*)d_in[0];
  const float* W = (const float*)d_in[1];
  const float* b = (const float*)d_in[2];
  float* out = (float*)d_out;

  const size_t xb_elems  = (size_t)MROWS * KP;
  const size_t wbt_elems = (size_t)NDIM * KP;
  const size_t need = (xb_elems + wbt_elems) * sizeof(u16);

  if (ws_size >= need) {
    u16* xb  = (u16*)d_ws;
    u16* wbt = xb + xb_elems;
    feat_kernel<<<MROWS, 256, 0, stream>>>(z, xb);
    wconv_kernel<<<dim3(KP / 64, NDIM / 64), 256, 0, stream>>>(W, b, wbt);
    gemm_kernel<<<(MROWS / 128) * (NDIM / 128), 256, 0, stream>>>(xb, wbt, out);
  } else {
    fallback_kernel<<<MROWS, 256, 0, stream>>>(z, W, b, out);
  }
}

// Round 2
// 302.534 us; speedup vs baseline: 1.8463x; 1.8463x over previous
//
#include <hip/hip_runtime.h>
#include <hip/hip_bf16.h>

#define KREAL 4369
#define KP    4416   // 69 * 64
#define NT    69     // K-tiles of 64
#define NDIM  4096
#define MROWS 8192

typedef unsigned short u16;
typedef __attribute__((ext_vector_type(8))) __bf16 bf16x8;
typedef __attribute__((ext_vector_type(8))) u16 u16x8;
typedef __attribute__((ext_vector_type(4))) float f32x4;

__device__ __forceinline__ u16 bf16rne(float f) {
  unsigned int u = __builtin_bit_cast(unsigned int, f);
  u += 0x7fffu + ((u >> 16) & 1u);
  return (u16)(u >> 16);
}

// ---------------- feature kernel: xb[row][t] = bf16(polyfeat(z_row)[t]) ----------------
__global__ void feat_kernel(const float* __restrict__ z, u16* __restrict__ xb) {
  __shared__ float zs[16];
  const int row = blockIdx.x;
  const int tid = threadIdx.x;
  if (tid < 16) zs[tid] = z[row * 16 + tid];
  __syncthreads();
  u16* xrow = xb + (size_t)row * KP;
  for (int g = tid; g < KP / 8; g += 256) {
    u16x8 pack;
#pragma unroll
    for (int e = 0; e < 8; ++e) {
      int t = g * 8 + e;
      float v;
      if (t >= KREAL) v = 0.0f;
      else if (t == 0) v = 1.0f;
      else if (t < 17) v = zs[t - 1];
      else if (t < 273) { int u = t - 17; v = zs[u >> 4] * zs[u & 15]; }
      else { int u = t - 273; v = zs[(u >> 8) & 15] * (zs[(u >> 4) & 15] * zs[u & 15]); }
      pack[e] = bf16rne(v);
    }
    *reinterpret_cast<u16x8*>(xrow + g * 8) = pack;
  }
}

// ------- W convert+transpose: wbt[d][t] = bf16(W[t][d] + (t==0 ? b[d] : 0)), t>=KREAL -> 0 -------
__global__ void wconv_kernel(const float* __restrict__ W, const float* __restrict__ bias,
                             u16* __restrict__ wbt) {
  __shared__ float tile[64][65];
  const int t0 = blockIdx.x * 64;
  const int d0 = blockIdx.y * 64;
  const int tid = threadIdx.x;
  const int dloc = tid & 63;
  const int rbase = tid >> 6;  // 0..3
#pragma unroll
  for (int rr = 0; rr < 16; ++rr) {
    const int r = rr * 4 + rbase;
    const int t = t0 + r;
    float v = 0.0f;
    if (t < KREAL) {
      v = W[(size_t)t * NDIM + d0 + dloc];
      if (t == 0) v += bias[d0 + dloc];
    }
    tile[r][dloc] = v;
  }
  __syncthreads();
#pragma unroll
  for (int round = 0; round < 2; ++round) {
    const int v = round * 256 + tid;
    const int d = v >> 3;   // 0..63
    const int tg = v & 7;   // 0..7
    u16x8 pack;
#pragma unroll
    for (int e = 0; e < 8; ++e) pack[e] = bf16rne(tile[tg * 8 + e][d]);
    *reinterpret_cast<u16x8*>(wbt + (size_t)(d0 + d) * KP + t0 + tg * 8) = pack;
  }
}

// ---------------- 256x256 8-phase GEMM: out = xb @ wbt^T (bias folded into wbt t=0) ----------------
#define GLOAD(gp, lp)                                                                     \
  __builtin_amdgcn_global_load_lds((const __attribute__((address_space(1))) unsigned int*)(gp), \
                                   (__attribute__((address_space(3))) unsigned int*)(lp), 16, 0, 0)

__device__ __forceinline__ void bar() {
  asm volatile("" ::: "memory");
  __builtin_amdgcn_s_barrier();
  asm volatile("" ::: "memory");
}

__global__ __launch_bounds__(512, 2) void gemm_kernel(const u16* __restrict__ xb,
                                                      const u16* __restrict__ wbt,
                                                      float* __restrict__ out) {
  __shared__ u16 lds[2 * 32768];  // 128 KiB: per buffer A[256][64] + B[256][64]

  // bijective XCD swizzle (nwg = 512, 512 % 8 == 0)
  const int bid = blockIdx.x;
  const int swz = (bid & 7) * 64 + (bid >> 3);
  const int mt = swz >> 4;   // 32 M-tiles
  const int ntile = swz & 15;  // 16 N-tiles
  const int brow = mt * 256;
  const int bcol = ntile * 256;

  const int tid  = threadIdx.x;
  const int lane = tid & 63;
  const int wid  = tid >> 6;   // 0..7
  const int wr   = wid >> 2;   // 0..1
  const int wc   = wid & 3;    // 0..3
  const int f    = lane & 15;
  const int q    = lane >> 4;
  const int f7   = f & 7;

  // staging geometry: wave-instr (wid,j) covers half-tile rows wid*16+j*8 .. +8
  // LDS dest is linear (base + lane*16); global source pre-swizzled: chunk = (lane&7) ^ (row&7)
  const int srow0 = wid * 16 + (lane >> 3);
  const int srow1 = srow0 + 8;
  const u16* gA0 = xb  + (size_t)(brow + srow0) * KP + ((lane & 7) ^ (srow0 & 7)) * 8;
  const u16* gA1 = xb  + (size_t)(brow + srow1) * KP + ((lane & 7) ^ (srow1 & 7)) * 8;
  const u16* gB0 = wbt + (size_t)(bcol + srow0) * KP + ((lane & 7) ^ (srow0 & 7)) * 8;
  const u16* gB1 = wbt + (size_t)(bcol + srow1) * KP + ((lane & 7) ^ (srow1 & 7)) * 8;
  const int dst0 = wid * 1024;        // u16 elems within half-region
  const int dst1 = dst0 + 512;

// stage half-tile H (0,1 = A halves; 2,3 = B halves) of K-tile U into buf (U&1)
#define STGH(U, H) do {                                                              \
    u16* _lb = lds + ((U) & 1) * 32768 + ((H) < 2 ? 0 : 16384) + ((H) & 1) * 8192;   \
    size_t _ko = (size_t)(U) * 64 + (size_t)((H) & 1) * 128 * KP;                    \
    if ((H) < 2) { GLOAD(gA0 + _ko, _lb + dst0); GLOAD(gA1 + _ko, _lb + dst1); }     \
    else         { GLOAD(gB0 + _ko, _lb + dst0); GLOAD(gB1 + _ko, _lb + dst1); }     \
  } while (0)

// swizzled ds_read_b128 of one MFMA fragment
#define RD_A(mi, kk) (*reinterpret_cast<const bf16x8*>(bufA + (wr * 128 + (mi) * 16 + f) * 64 + (((kk) * 4 + q) ^ f7) * 8))
#define RD_B(ni, kk) (*reinterpret_cast<const bf16x8*>(bufB + (wc * 64 + (ni) * 16 + f) * 64 + (((kk) * 4 + q) ^ f7) * 8))

#define RDA4(MOFF) do {                                                              \
    _Pragma("unroll") for (int _i = 0; _i < 4; ++_i) {                               \
      a_[_i][0] = RD_A((MOFF) + _i, 0); a_[_i][1] = RD_A((MOFF) + _i, 1); }          \
  } while (0)
#define RDB2(NOFF) do {                                                              \
    _Pragma("unroll") for (int _i = 0; _i < 2; ++_i) {                               \
      b_[(NOFF) + _i][0] = RD_B((NOFF) + _i, 0); b_[(NOFF) + _i][1] = RD_B((NOFF) + _i, 1); } \
  } while (0)

// one C-quadrant (4 M-frags x 2 N-frags x K=64) = 16 MFMA, setprio-wrapped (T5)
#define QUAD(MOFF, NOFF) do {                                                        \
    __builtin_amdgcn_s_setprio(1);                                                   \
    _Pragma("unroll") for (int _m = 0; _m < 4; ++_m)                                 \
    _Pragma("unroll") for (int _n = 0; _n < 2; ++_n)                                 \
    _Pragma("unroll") for (int _k = 0; _k < 2; ++_k)                                 \
      acc[(MOFF) + _m][(NOFF) + _n] = __builtin_amdgcn_mfma_f32_16x16x32_bf16(       \
          a_[_m][_k], b_[(NOFF) + _n][_k], acc[(MOFF) + _m][(NOFF) + _n], 0, 0, 0);  \
    __builtin_amdgcn_s_setprio(0);                                                   \
  } while (0)

  f32x4 acc[8][4] = {};
  bf16x8 a_[4][2], b_[4][2];
  const u16 *bufA, *bufB;

  // prologue: tile0 fully + tile1 half0; keep tile1-h0's 2 loads in flight
  STGH(0, 0); STGH(0, 1); STGH(0, 2); STGH(0, 3);
  STGH(1, 0);
  asm volatile("s_waitcnt vmcnt(2)" ::: "memory");
  bar();

  for (int t = 0; t < NT - 1; t += 2) {
    // ---------------- tile t (buf 0) ----------------
    bufA = lds; bufB = lds + 16384;
    RDA4(0); RDB2(0);
    STGH(t + 1, 1);
    bar(); QUAD(0, 0); bar();

    RDB2(2);
    STGH(t + 1, 2);
    bar(); QUAD(0, 2); bar();

    RDA4(4);
    STGH(t + 1, 3);
    bar(); QUAD(4, 2); bar();

    STGH(t + 2, 0);                     // buf0 reads all retired at phase-3 barrier
    asm volatile("s_waitcnt vmcnt(2)" ::: "memory");   // tile t+1 resident (t+2 h0 in flight)
    bar(); QUAD(4, 0); bar();

    // ---------------- tile t+1 (buf 1) ----------------
    bufA = lds + 32768; bufB = bufA + 16384;
    RDA4(0); RDB2(0);
    STGH(t + 2, 1);
    bar(); QUAD(0, 0); bar();

    RDB2(2);
    STGH(t + 2, 2);
    bar(); QUAD(0, 2); bar();

    RDA4(4);
    STGH(t + 2, 3);
    bar(); QUAD(4, 2); bar();

    if (t + 3 < NT) {
      STGH(t + 3, 0);
      asm volatile("s_waitcnt vmcnt(2)" ::: "memory"); // tile t+2 resident (t+3 h0 in flight)
    } else {
      asm volatile("s_waitcnt vmcnt(0)" ::: "memory"); // last: drain everything
    }
    bar(); QUAD(4, 0); bar();
  }

  // ---------------- tail tile NT-1 = 68 (buf 0), fully resident ----------------
  bufA = lds; bufB = lds + 16384;
  RDA4(0); RDB2(0); QUAD(0, 0);
  RDB2(2);          QUAD(0, 2);
  RDA4(4);          QUAD(4, 2); QUAD(4, 0);

  // epilogue: C/D layout col = lane&15, row = (lane>>4)*4 + j
  const int r0 = brow + wr * 128 + q * 4;
  const int c0 = bcol + wc * 64 + f;
#pragma unroll
  for (int mi = 0; mi < 8; ++mi)
#pragma unroll
    for (int ni = 0; ni < 4; ++ni) {
#pragma unroll
      for (int j = 0; j < 4; ++j)
        out[(size_t)(r0 + mi * 16 + j) * NDIM + (c0 + ni * 16)] = acc[mi][ni][j];
    }
}

// ---------------- fallback (ws too small): correct fp32 path ----------------
__global__ void fallback_kernel(const float* __restrict__ z, const float* __restrict__ W,
                                const float* __restrict__ bias, float* __restrict__ out) {
  __shared__ float feat[KREAL];
  const int row = blockIdx.x;
  const int tid = threadIdx.x;
  for (int t = tid; t < KREAL; t += 256) {
    float v;
    if (t == 0) v = 1.0f;
    else if (t < 17) v = z[row * 16 + t - 1];
    else if (t < 273) { int u = t - 17; v = z[row * 16 + (u >> 4)] * z[row * 16 + (u & 15)]; }
    else { int u = t - 273; v = z[row * 16 + ((u >> 8) & 15)] * (z[row * 16 + ((u >> 4) & 15)] * z[row * 16 + (u & 15)]); }
    feat[t] = v;
  }
  __syncthreads();
  float acc[16];
#pragma unroll
  for (int j = 0; j < 16; ++j) acc[j] = bias[tid + 256 * j];
  for (int t = 0; t < KREAL; ++t) {
    const float fv = feat[t];
    const float* wrow = W + (size_t)t * NDIM;
#pragma unroll
    for (int j = 0; j < 16; ++j) acc[j] = fmaf(fv, wrow[tid + 256 * j], acc[j]);
  }
  float* orow = out + (size_t)row * NDIM;
#pragma unroll
  for (int j = 0; j < 16; ++j) orow[tid + 256 * j] = acc[j];
}

extern "C" void kernel_launch(void* const* d_in, const int* in_sizes, int n_in,
                              void* d_out, int out_size, void* d_ws, size_t ws_size,
                              hipStream_t stream) {
  const float* z = (const float*)d_in[0];
  const float* W = (const float*)d_in[1];
  const float* b = (const float*)d_in[2];
  float* out = (float*)d_out;

  const size_t xb_elems  = (size_t)MROWS * KP;
  const size_t wbt_elems = (size_t)NDIM * KP;
  const size_t need = (xb_elems + wbt_elems) * sizeof(u16);

  if (ws_size >= need) {
    u16* xb  = (u16*)d_ws;
    u16* wbt = xb + xb_elems;
    feat_kernel<<<MROWS, 256, 0, stream>>>(z, xb);
    wconv_kernel<<<dim3(KP / 64, NDIM / 64), 256, 0, stream>>>(W, b, wbt);
    gemm_kernel<<<(MROWS / 256) * (NDIM / 256), 512, 0, stream>>>(xb, wbt, out);
  } else {
    fallback_kernel<<<MROWS, 256, 0, stream>>>(z, W, b, out);
  }
}

// Round 3
// 293.232 us; speedup vs baseline: 1.9049x; 1.0317x over previous
//
#include <hip/hip_runtime.h>
#include <hip/hip_bf16.h>

#define KREAL 4369
#define KP    4416   // 69 * 64
#define NT    69     // K-tiles of 64
#define NDIM  4096
#define MROWS 8192

typedef unsigned short u16;
typedef __attribute__((ext_vector_type(8))) __bf16 bf16x8;
typedef __attribute__((ext_vector_type(8))) u16 u16x8;
typedef __attribute__((ext_vector_type(4))) float f32x4;

__device__ __forceinline__ u16 bf16rne(float f) {
  unsigned int u = __builtin_bit_cast(unsigned int, f);
  u += 0x7fffu + ((u >> 16) & 1u);
  return (u16)(u >> 16);
}

// ---------------- feature kernel: xb[row][t] = bf16(polyfeat(z_row)[t]) ----------------
__global__ void feat_kernel(const float* __restrict__ z, u16* __restrict__ xb) {
  __shared__ float zs[16];
  const int row = blockIdx.x;
  const int tid = threadIdx.x;
  if (tid < 16) zs[tid] = z[row * 16 + tid];
  __syncthreads();
  u16* xrow = xb + (size_t)row * KP;
  for (int g = tid; g < KP / 8; g += 256) {
    u16x8 pack;
#pragma unroll
    for (int e = 0; e < 8; ++e) {
      int t = g * 8 + e;
      float v;
      if (t >= KREAL) v = 0.0f;
      else if (t == 0) v = 1.0f;
      else if (t < 17) v = zs[t - 1];
      else if (t < 273) { int u = t - 17; v = zs[u >> 4] * zs[u & 15]; }
      else { int u = t - 273; v = zs[(u >> 8) & 15] * (zs[(u >> 4) & 15] * zs[u & 15]); }
      pack[e] = bf16rne(v);
    }
    *reinterpret_cast<u16x8*>(xrow + g * 8) = pack;
  }
}

// ------- W convert+transpose: wbt[d][t] = bf16(W[t][d] + (t==0 ? b[d] : 0)), t>=KREAL -> 0 -------
__global__ void wconv_kernel(const float* __restrict__ W, const float* __restrict__ bias,
                             u16* __restrict__ wbt) {
  __shared__ float tile[64][68];
  const int t0 = blockIdx.x * 64;
  const int d0 = blockIdx.y * 64;
  const int tid = threadIdx.x;
  const int d4 = (tid & 15) * 4;   // float4 column within tile
  const int rb = tid >> 4;         // 0..15
#pragma unroll
  for (int p = 0; p < 4; ++p) {
    const int r = p * 16 + rb;
    const int t = t0 + r;
    f32x4 v = {0.f, 0.f, 0.f, 0.f};
    if (t < KREAL) {
      v = *reinterpret_cast<const f32x4*>(W + (size_t)t * NDIM + d0 + d4);
      if (t == 0) {
        f32x4 bb = *reinterpret_cast<const f32x4*>(bias + d0 + d4);
        v.x += bb.x; v.y += bb.y; v.z += bb.z; v.w += bb.w;
      }
    }
#pragma unroll
    for (int j = 0; j < 4; ++j) tile[r][d4 + j] = v[j];
  }
  __syncthreads();
#pragma unroll
  for (int round = 0; round < 2; ++round) {
    const int v = round * 256 + tid;
    const int d = v >> 3;   // 0..63
    const int tg = v & 7;   // 0..7
    u16x8 pack;
#pragma unroll
    for (int e = 0; e < 8; ++e) pack[e] = bf16rne(tile[tg * 8 + e][d]);
    *reinterpret_cast<u16x8*>(wbt + (size_t)(d0 + d) * KP + t0 + tg * 8) = pack;
  }
}

// ---------------- 256x256 8-phase GEMM: out = xb @ wbt^T (bias folded into wbt t=0) ----------------
#define GLOAD(gp, lp)                                                                     \
  __builtin_amdgcn_global_load_lds((const __attribute__((address_space(1))) unsigned int*)(gp), \
                                   (__attribute__((address_space(3))) unsigned int*)(lp), 16, 0, 0)

__device__ __forceinline__ void bar() {
  asm volatile("" ::: "memory");
  __builtin_amdgcn_s_barrier();
  asm volatile("" ::: "memory");
}

__global__ __launch_bounds__(512, 2) void gemm_kernel(const u16* __restrict__ xb,
                                                      const u16* __restrict__ wbt,
                                                      float* __restrict__ out) {
  __shared__ u16 lds[2 * 32768];  // 128 KiB: per buffer A[256][64] + B[256][64]

  // XCD swizzle, chunked 4Mx8N per concurrent 32-block round (nwg=512, 512%8==0)
  const int bid  = blockIdx.x;
  const int xcd  = bid & 7;
  const int idx  = bid >> 3;            // 0..63 within XCD
  const int mtl  = (idx >> 3) & 3;      // 4 M-tiles per XCD
  const int ntl  = (idx & 7) | ((idx >> 5) << 3);  // 8 N-tiles per round, 2 rounds
  const int brow = (xcd * 4 + mtl) * 256;
  const int bcol = ntl * 256;

  const int tid  = threadIdx.x;
  const int lane = tid & 63;
  const int wid  = tid >> 6;   // 0..7
  const int wr   = wid >> 2;   // 0..1
  const int wc   = wid & 3;    // 0..3
  const int f    = lane & 15;
  const int q    = lane >> 4;
  const int f7   = f & 7;

  // staging geometry: wave-instr (wid,j) covers half-tile rows wid*16+j*8 .. +8
  // LDS dest linear (base + lane*16); global source pre-swizzled: chunk = (lane&7) ^ (row&7)
  const int srow0 = wid * 16 + (lane >> 3);
  const int srow1 = srow0 + 8;
  const u16* gA0 = xb  + (size_t)(brow + srow0) * KP + ((lane & 7) ^ (srow0 & 7)) * 8;
  const u16* gA1 = xb  + (size_t)(brow + srow1) * KP + ((lane & 7) ^ (srow1 & 7)) * 8;
  const u16* gB0 = wbt + (size_t)(bcol + srow0) * KP + ((lane & 7) ^ (srow0 & 7)) * 8;
  const u16* gB1 = wbt + (size_t)(bcol + srow1) * KP + ((lane & 7) ^ (srow1 & 7)) * 8;
  const int dst0 = wid * 1024;        // u16 elems within half-region
  const int dst1 = dst0 + 512;

// stage half-tile H (0,1 = A halves; 2,3 = B halves) of K-tile U into buf (U&1)
#define STGH(U, H) do {                                                              \
    u16* _lb = lds + ((U) & 1) * 32768 + ((H) < 2 ? 0 : 16384) + ((H) & 1) * 8192;   \
    size_t _ko = (size_t)(U) * 64 + (size_t)((H) & 1) * 128 * KP;                    \
    if ((H) < 2) { GLOAD(gA0 + _ko, _lb + dst0); GLOAD(gA1 + _ko, _lb + dst1); }     \
    else         { GLOAD(gB0 + _ko, _lb + dst0); GLOAD(gB1 + _ko, _lb + dst1); }     \
  } while (0)

// swizzled ds_read_b128 of one MFMA fragment
#define RD_A(mi, kk) (*reinterpret_cast<const bf16x8*>(bufA + (wr * 128 + (mi) * 16 + f) * 64 + (((kk) * 4 + q) ^ f7) * 8))
#define RD_B(ni, kk) (*reinterpret_cast<const bf16x8*>(bufB + (wc * 64 + (ni) * 16 + f) * 64 + (((kk) * 4 + q) ^ f7) * 8))

#define RDA4(MOFF) do {                                                              \
    _Pragma("unroll") for (int _i = 0; _i < 4; ++_i) {                               \
      a_[_i][0] = RD_A((MOFF) + _i, 0); a_[_i][1] = RD_A((MOFF) + _i, 1); }          \
  } while (0)
#define RDB2(NOFF) do {                                                              \
    _Pragma("unroll") for (int _i = 0; _i < 2; ++_i) {                               \
      b_[(NOFF) + _i][0] = RD_B((NOFF) + _i, 0); b_[(NOFF) + _i][1] = RD_B((NOFF) + _i, 1); } \
  } while (0)

// one C-quadrant (4 M-frags x 2 N-frags x K=64) = 16 MFMA, setprio-wrapped (T5)
#define QUAD(MOFF, NOFF) do {                                                        \
    __builtin_amdgcn_s_setprio(1);                                                   \
    _Pragma("unroll") for (int _m = 0; _m < 4; ++_m)                                 \
    _Pragma("unroll") for (int _n = 0; _n < 2; ++_n)                                 \
    _Pragma("unroll") for (int _k = 0; _k < 2; ++_k)                                 \
      acc[(MOFF) + _m][(NOFF) + _n] = __builtin_amdgcn_mfma_f32_16x16x32_bf16(       \
          a_[_m][_k], b_[(NOFF) + _n][_k], acc[(MOFF) + _m][(NOFF) + _n], 0, 0, 0);  \
    __builtin_amdgcn_s_setprio(0);                                                   \
  } while (0)

  f32x4 acc[8][4] = {};
  bf16x8 a_[4][2], b_[4][2];
  const u16 *bufA, *bufB;

  // prologue: tile0 fully (8 loads) + tile1 h0,h1 (4 loads, A halves)
  STGH(0, 0); STGH(0, 1); STGH(0, 2); STGH(0, 3);
  STGH(1, 0); STGH(1, 1);
  asm volatile("s_waitcnt vmcnt(4)" ::: "memory");
  bar();

  // schedule per tile t: ph1 stage (t+1,h2); ph2 stage (t+1,h3);
  //                      ph4 stage (t+2,h0)+(t+2,h1) then fence vmcnt(4)
  // (t+1's h0,h1 were staged at t-1's ph4: 4 phases of slack; h2: 3; h3: 2)
  for (int t = 0; t < NT - 1; t += 2) {
    // ---------------- tile t (buf 0) ----------------
    bufA = lds; bufB = lds + 16384;
    RDA4(0); RDB2(0);
    STGH(t + 1, 2);
    bar(); QUAD(0, 0); bar();

    RDB2(2);
    STGH(t + 1, 3);
    bar(); QUAD(0, 2); bar();

    RDA4(4);
    bar(); QUAD(4, 2); bar();

    STGH(t + 2, 0); STGH(t + 2, 1);     // buf0 fully retired at ph3-end barrier
    asm volatile("s_waitcnt vmcnt(4)" ::: "memory");   // tile t+1 resident
    bar(); QUAD(4, 0); bar();

    // ---------------- tile t+1 (buf 1) ----------------
    bufA = lds + 32768; bufB = bufA + 16384;
    RDA4(0); RDB2(0);
    STGH(t + 2, 2);
    bar(); QUAD(0, 0); bar();

    RDB2(2);
    STGH(t + 2, 3);
    bar(); QUAD(0, 2); bar();

    RDA4(4);
    bar(); QUAD(4, 2); bar();

    if (t + 3 < NT) {
      STGH(t + 3, 0); STGH(t + 3, 1);
      asm volatile("s_waitcnt vmcnt(4)" ::: "memory"); // tile t+2 resident
    } else {
      asm volatile("s_waitcnt vmcnt(0)" ::: "memory"); // last: drain everything
    }
    bar(); QUAD(4, 0); bar();
  }

  // ---------------- tail tile NT-1 = 68 (buf 0), fully resident ----------------
  bufA = lds; bufB = lds + 16384;
  RDA4(0); RDB2(0); QUAD(0, 0);
  RDB2(2);          QUAD(0, 2);
  RDA4(4);          QUAD(4, 2); QUAD(4, 0);

  // epilogue: C/D layout col = lane&15, row = (lane>>4)*4 + j
  const int r0 = brow + wr * 128 + q * 4;
  const int c0 = bcol + wc * 64 + f;
#pragma unroll
  for (int mi = 0; mi < 8; ++mi)
#pragma unroll
    for (int ni = 0; ni < 4; ++ni) {
#pragma unroll
      for (int j = 0; j < 4; ++j)
        out[(size_t)(r0 + mi * 16 + j) * NDIM + (c0 + ni * 16)] = acc[mi][ni][j];
    }
}

// ---------------- fallback (ws too small): correct fp32 path ----------------
__global__ void fallback_kernel(const float* __restrict__ z, const float* __restrict__ W,
                                const float* __restrict__ bias, float* __restrict__ out) {
  __shared__ float feat[KREAL];
  const int row = blockIdx.x;
  const int tid = threadIdx.x;
  for (int t = tid; t < KREAL; t += 256) {
    float v;
    if (t == 0) v = 1.0f;
    else if (t < 17) v = z[row * 16 + t - 1];
    else if (t < 273) { int u = t - 17; v = z[row * 16 + (u >> 4)] * z[row * 16 + (u & 15)]; }
    else { int u = t - 273; v = z[row * 16 + ((u >> 8) & 15)] * (z[row * 16 + ((u >> 4) & 15)] * z[row * 16 + (u & 15)]); }
    feat[t] = v;
  }
  __syncthreads();
  float acc[16];
#pragma unroll
  for (int j = 0; j < 16; ++j) acc[j] = bias[tid + 256 * j];
  for (int t = 0; t < KREAL; ++t) {
    const float fv = feat[t];
    const float* wrow = W + (size_t)t * NDIM;
#pragma unroll
    for (int j = 0; j < 16; ++j) acc[j] = fmaf(fv, wrow[tid + 256 * j], acc[j]);
  }
  float* orow = out + (size_t)row * NDIM;
#pragma unroll
  for (int j = 0; j < 16; ++j) orow[tid + 256 * j] = acc[j];
}

extern "C" void kernel_launch(void* const* d_in, const int* in_sizes, int n_in,
                              void* d_out, int out_size, void* d_ws, size_t ws_size,
                              hipStream_t stream) {
  const float* z = (const float*)d_in[0];
  const float* W = (const float*)d_in[1];
  const float* b = (const float*)d_in[2];
  float* out = (float*)d_out;

  const size_t xb_elems  = (size_t)MROWS * KP;
  const size_t wbt_elems = (size_t)NDIM * KP;
  const size_t need = (xb_elems + wbt_elems) * sizeof(u16);

  if (ws_size >= need) {
    u16* xb  = (u16*)d_ws;
    u16* wbt = xb + xb_elems;
    feat_kernel<<<MROWS, 256, 0, stream>>>(z, xb);
    wconv_kernel<<<dim3(KP / 64, NDIM / 64), 256, 0, stream>>>(W, b, wbt);
    gemm_kernel<<<(MROWS / 256) * (NDIM / 256), 512, 0, stream>>>(xb, wbt, out);
  } else {
    fallback_kernel<<<MROWS, 256, 0, stream>>>(z, W, b, out);
  }
}